// Round 5
// baseline (20422.600 us; speedup 1.0000x reference)
//
#include <hip/hip_runtime.h>
#include <math.h>

#define LL 256
#define BB 256
#define HH 256
#define CC 16
#define YY 32
#define HC (HH*CC)     // 4096
#define NSTEP (LL-1)   // 255
#define NBG 32         // batch groups
#define BGB 8          // batches per group
#define HCH 32         // h per chunk (=> 512 W2 cols per block)
#define TPB 1024
#define NJS 8          // phase-B j-split slices

typedef __attribute__((ext_vector_type(4))) float f32x4;   // packed fp32 (v_pk_fma_f32 pairs)

// fast tanh: 1 - 2/(e^{2x}+1). Saturates correctly for |x| large (inf -> 1,
// 0 -> -1), no NaN for finite x, ~2 ulp. Replaces the ~100-inst ocml libcall.
// IDENTICAL to the r0 baseline (bit-exact numerics frozen).
__device__ __forceinline__ float fast_tanh(float x) {
    float e = __expf(2.0f * x);
    return 1.0f - 2.0f / (e + 1.0f);
}

// coherence-point (device-coherent) access: bypasses the non-coherent
// per-XCD L2s. Used ONLY for the small cross-block z / hid exchange.
__device__ __forceinline__ float ld_coh(const float* p) {
    return __hip_atomic_load(p, __ATOMIC_RELAXED, __HIP_MEMORY_SCOPE_AGENT);
}
__device__ __forceinline__ float2 ld_coh2(const float* p) {
    union { unsigned long long u; float2 f; } cv;
    cv.u = __hip_atomic_load((const unsigned long long*)p,
                             __ATOMIC_RELAXED, __HIP_MEMORY_SCOPE_AGENT);
    return cv.f;
}
__device__ __forceinline__ void st_coh(float* p, float v) {
    __hip_atomic_store(p, v, __ATOMIC_RELAXED, __HIP_MEMORY_SCOPE_AGENT);
}

// 8-way sibling barrier, monotonic per-group counter (no reset).
// __syncthreads() drains vmem (vmcnt(0) before s_barrier) so all coherent
// stores are visible before the arrival add. 32 groups on 32 distinct lines.
__device__ __forceinline__ void bg_barrier(unsigned* cnt, unsigned target) {
    __syncthreads();
    if (threadIdx.x == 0) {
        __hip_atomic_fetch_add(cnt, 1u, __ATOMIC_RELAXED, __HIP_MEMORY_SCOPE_AGENT);
        while (__hip_atomic_load(cnt, __ATOMIC_RELAXED, __HIP_MEMORY_SCOPE_AGENT) < target)
            __builtin_amdgcn_s_sleep(1);
    }
    __syncthreads();
}

// ---------------------------------------------------------------------------
// persistent scan: 256 blocks = 32 bg x 8 hc, 1024 threads (16 waves/CU).
// block (bg,hc): batches b0..b0+7, h-columns h0..h0+31 (W2 cols n0..n0+511).
// phase-B thread: 4 cols x 8 batches x 32 j  (j-split 8).
// NUMERICS ARE BIT-IDENTICAL TO THE PASSING r0 BASELINE: every fp32 FMA chain
// has the same elements in the same order; only LDS layout (hidT transpose ->
// natural hid_loc, conflict-free) and FMA packing (v_pk_fma_f32 pairs of
// independent chains) changed.
// ---------------------------------------------------------------------------
__global__ void __launch_bounds__(TPB)
k_scan(const float* __restrict__ us, const float* __restrict__ W1,
       const float* __restrict__ b1, const float* __restrict__ W2,
       const float* __restrict__ b2, float* __restrict__ zs,
       float* __restrict__ hidG, unsigned* __restrict__ barG) {
    __shared__ float smem[NJS * BGB * 512 + 2048 + 2048 + 512 + 128 + 32];
    float* psum    = smem;                         // [8][8][512]  128 KB
    float* pa      = smem;                         // alias [32][256] (phase A)
    float* z_loc   = smem + NJS * BGB * 512;       // [8][256]     8 KB
    float* hid_loc = z_loc + BGB * HH;             // [8][256]     8 KB (was hidT[256][8])
    float* b2s     = hid_loc + BGB * HH;           // [512]
    float* dvs     = b2s + 512;                    // [8][16]
    float* b1s     = dvs + 128;                    // [32]

    const int bg = blockIdx.x >> 3;
    const int hc = blockIdx.x & 7;
    const int t  = threadIdx.x;
    const int b0 = bg * BGB;
    const int h0 = hc * HCH;
    const int n0 = h0 * CC;                      // = hc*512

    // ---- one-time preload ----
    // phase-A W1 slice in registers: thread (ajc = t>>5 j-chunk of 8, ah = t&31)
    const int ajc = t >> 5;                      // 0..31
    const int ah  = t & 31;
    float w1r[8];
    #pragma unroll
    for (int r = 0; r < 8; r++)
        w1r[r] = W1[(size_t)(ajc * 8 + r) * HH + h0 + ah];
    for (int i = t; i < 512; i += TPB) b2s[i] = b2[n0 + i];
    if (t < HCH) b1s[t] = b1[h0 + t];
    __syncthreads();

    unsigned* cnt = barG + (size_t)bg * 64;      // 256-B line per group

    // staging indices (8-byte coherent loads): thread -> (b = t>>7, pair t&127)
    const int sb  = t >> 7;                      // 0..7
    const int sj2 = (t & 127) << 1;              // 0,2,..,254
    // phase-B indices: thread (jsp = t>>7 -> 32 j's, 4 cols at ct)
    const int jsp = t >> 7;                      // 0..7
    const int ct  = (t & 127) << 2;              // 0..508
    // dz indices
    const int col = t & 511;
    const int bh  = (t >> 9) << 2;               // 0 or 4

    for (int k = 0; k < NSTEP; k++) {
        const size_t zk = (size_t)k * (BB * HH);

        // ---- stage z_loc (coherent 8B, coalesced) + dvs ----
        {
            float2 v = ld_coh2(&zs[zk + (size_t)(b0 + sb) * HH + sj2]);
            *(float2*)&z_loc[sb * HH + sj2] = v;
        }
        if (t < BGB * CC) {
            int b = t >> 4, c = t & 15;
            int kk = (k < 1) ? 1 : k;
            float v = 1.0f;                      // c==0: ts diff == 1
            if (c > 0)
                v = us[((size_t)kk * BB + b0 + b) * (CC - 1) + c - 1]
                  - us[((size_t)(kk - 1) * BB + b0 + b) * (CC - 1) + c - 1];
            dvs[b * CC + c] = v;
        }
        __syncthreads();

        // ---- phase A: partial hid[b][h0+ah] over 8 j's (W1 in regs) ----
        // UNCHANGED from r0 (bit-exact).
        {
            float acc[BGB];
            #pragma unroll
            for (int b = 0; b < BGB; b++) acc[b] = 0.f;
            #pragma unroll
            for (int r2 = 0; r2 < 2; r2++) {
                #pragma unroll
                for (int b = 0; b < BGB; b++) {
                    float4 zv = *(const float4*)&z_loc[b * HH + ajc * 8 + r2 * 4];
                    acc[b] += zv.x * w1r[r2 * 4 + 0] + zv.y * w1r[r2 * 4 + 1]
                            + zv.z * w1r[r2 * 4 + 2] + zv.w * w1r[r2 * 4 + 3];
                }
            }
            #pragma unroll
            for (int b = 0; b < BGB; b++)
                pa[ajc * 256 + b * HCH + ah] = acc[b];  // lane-stride 1: free
        }
        __syncthreads();
        if (t < BGB * HCH) {                     // reduce 32 partials, relu, publish
            float s = b1s[t & 31];
            #pragma unroll
            for (int q = 0; q < 32; q++) s += pa[q * 256 + t];  // stride 1
            st_coh(&hidG[(size_t)(b0 + (t >> 5)) * HH + h0 + (t & 31)],
                   fmaxf(s, 0.f));
        }
        bg_barrier(cnt, 8u * (2u * (unsigned)k + 1u));   // hid complete

        // ---- stage hid_loc NATURAL layout (coherent 8B, coalesced) ----
        // replaces hidT[j][b] transpose: write lane-stride is 8B -> 2-way
        // bank aliasing (free) instead of 64B stride (32-way conflict).
        {
            float2 v = ld_coh2(&hidG[(size_t)(b0 + sb) * HH + sj2]);
            *(float2*)&hid_loc[sb * HH + sj2] = v;
        }
        __syncthreads();

        // ---- phase B: hid(8x256) @ W2-slice(256x512) ----
        // j-step-4 restructure: h-values read as float4 BROADCASTS from the
        // natural hid_loc row (conflict-free). Each acc[b][c] chain receives
        // the SAME products in the SAME j-order as r0 -> bit-identical.
        // f32x4 mul+add contracts to per-element fmuladd = same rounding as
        // r0's scalar contracted FMAs, packed 2-per-instruction.
        {
            f32x4 acc[BGB];
            #pragma unroll
            for (int b = 0; b < BGB; b++) acc[b] = (f32x4){0.f, 0.f, 0.f, 0.f};
            const int jb = jsp * 32;
            const float* w2p = &W2[(size_t)jb * HC + n0 + ct];
            #pragma unroll
            for (int jq = 0; jq < 32; jq += 4) {
                f32x4 w0 = *(const f32x4*)&w2p[(size_t)(jq + 0) * HC];
                f32x4 w1 = *(const f32x4*)&w2p[(size_t)(jq + 1) * HC];
                f32x4 w2v = *(const f32x4*)&w2p[(size_t)(jq + 2) * HC];
                f32x4 w3 = *(const f32x4*)&w2p[(size_t)(jq + 3) * HC];
                #pragma unroll
                for (int b = 0; b < BGB; b++) {
                    f32x4 h4 = *(const f32x4*)&hid_loc[b * HH + jb + jq]; // bcast
                    acc[b] = h4.x * w0  + acc[b];
                    acc[b] = h4.y * w1  + acc[b];
                    acc[b] = h4.z * w2v + acc[b];
                    acc[b] = h4.w * w3  + acc[b];
                }
            }
            #pragma unroll
            for (int b = 0; b < BGB; b++)
                *(f32x4*)&psum[((jsp * BGB + b) << 9) + ct] = acc[b];
        }
        __syncthreads();

        // ---- dz + z update: lane owns col; 16-lane shfl c-reduction ----
        // UNCHANGED from r0 (bit-exact).
        {
            #pragma unroll
            for (int q = 0; q < 4; q++) {
                int b = bh + q;
                float g = b2s[col];
                #pragma unroll
                for (int s = 0; s < NJS; s++)
                    g += psum[((s * BGB + b) << 9) + col];   // stride-1
                float v = fast_tanh(g) * dvs[b * CC + (col & 15)];
                v += __shfl_xor(v, 1);
                v += __shfl_xor(v, 2);
                v += __shfl_xor(v, 4);
                v += __shfl_xor(v, 8);
                if ((col & 15) == 0) {
                    int hl = col >> 4;
                    st_coh(&zs[zk + (size_t)(BB * HH) + (size_t)(b0 + b) * HH + h0 + hl],
                           z_loc[b * HH + h0 + hl] + v);     // dt == 1
                }
            }
        }
        bg_barrier(cnt, 8u * (2u * (unsigned)k + 2u));       // z[k+1] complete
    }
}

// ---------------------------------------------------------------------------
// out = tanh(z_seq @ dW1 + db1) @ dW2 + db2   (zs natural layout [l*B+b][H])
// grid: L*B/16 = 4096 blocks, 256 threads — UNCHANGED from r0.
// ---------------------------------------------------------------------------
__global__ void k_out(const float* __restrict__ zseq, const float* __restrict__ dW1,
                      const float* __restrict__ db1, const float* __restrict__ dW2,
                      const float* __restrict__ db2, float* __restrict__ out) {
    __shared__ float zt[16][HH];       // 16 KB
    __shared__ float act[16][2 * HH];  // 32 KB
    int r0 = blockIdx.x * 16;
    int t  = threadIdx.x;
    {
        const float4* src = (const float4*)(zseq + (size_t)r0 * HH);
        float4* dst = (float4*)&zt[0][0];
        for (int i = t; i < 1024; i += 256) dst[i] = src[i];
    }
    __syncthreads();
    {   // phase 1: act = tanh(z @ dW1 + db1), 512 cols
        int c0  = (t & 127) * 4;
        int rr0 = (t >> 7) * 8;
        float a[8][4];
        #pragma unroll
        for (int i = 0; i < 8; i++)
            #pragma unroll
            for (int q = 0; q < 4; q++) a[i][q] = 0.f;
        for (int j = 0; j < HH; j++) {
            float4 w = *(const float4*)&dW1[(size_t)j * 2 * HH + c0];
            #pragma unroll
            for (int i = 0; i < 8; i++) {
                float zv = zt[rr0 + i][j];
                a[i][0] += zv * w.x; a[i][1] += zv * w.y;
                a[i][2] += zv * w.z; a[i][3] += zv * w.w;
            }
        }
        float4 bias = *(const float4*)&db1[c0];
        #pragma unroll
        for (int i = 0; i < 8; i++) {
            act[rr0 + i][c0 + 0] = fast_tanh(a[i][0] + bias.x);
            act[rr0 + i][c0 + 1] = fast_tanh(a[i][1] + bias.y);
            act[rr0 + i][c0 + 2] = fast_tanh(a[i][2] + bias.z);
            act[rr0 + i][c0 + 3] = fast_tanh(a[i][3] + bias.w);
        }
    }
    __syncthreads();
    {   // phase 2: out = act @ dW2 + db2
        int rl = t >> 4;
        int y2 = t & 15;
        float o0 = 0.f, o1 = 0.f;
        #pragma unroll 4
        for (int j = 0; j < 2 * HH; j++) {
            float av = act[rl][j];
            float2 w = *(const float2*)&dW2[(size_t)j * YY + y2 * 2];
            o0 += av * w.x; o1 += av * w.y;
        }
        float2 bias = *(const float2*)&db2[y2 * 2];
        out[(size_t)(r0 + rl) * YY + y2 * 2]     = o0 + bias.x;
        out[(size_t)(r0 + rl) * YY + y2 * 2 + 1] = o1 + bias.y;
    }
}

// ---------------------------------------------------------------------------
extern "C" void kernel_launch(void* const* d_in, const int* in_sizes, int n_in,
                              void* d_out, int out_size, void* d_ws, size_t ws_size,
                              hipStream_t stream) {
    const float* us  = (const float*)d_in[1];
    const float* h0  = (const float*)d_in[2];
    const float* W1  = (const float*)d_in[3];
    const float* b1  = (const float*)d_in[4];
    const float* W2  = (const float*)d_in[5];
    const float* b2  = (const float*)d_in[6];
    const float* dW1 = (const float*)d_in[7];
    const float* db1 = (const float*)d_in[8];
    const float* dW2 = (const float*)d_in[9];
    const float* db2 = (const float*)d_in[10];
    float* out = (float*)d_out;

    float* zs   = (float*)d_ws;                          // L*B*H = 64 MB, [l*B+b][h]
    float* hidG = zs + (size_t)LL * BB * HH;             // B*H   = 256 KB
    unsigned* barG = (unsigned*)(hidG + (size_t)BB * HH); // 32 x 256 B = 8 KB

    hipMemcpyAsync(zs, h0, (size_t)BB * HH * sizeof(float),
                   hipMemcpyDeviceToDevice, stream);
    hipMemsetAsync(barG, 0, NBG * 64 * sizeof(unsigned), stream);

    k_scan<<<NBG * 8, TPB, 0, stream>>>(us, W1, b1, W2, b2, zs, hidG, barG);
    k_out<<<LL * BB / 16, 256, 0, stream>>>(zs, dW1, db1, dW2, db2, out);
}

// Round 6
// 3513.371 us; speedup vs baseline: 5.8128x; 5.8128x over previous
//
#include <hip/hip_runtime.h>
#include <math.h>

#define LL 256
#define BB 256
#define HH 256
#define CC 16
#define YY 32
#define HC (HH*CC)     // 4096
#define NSTEP (LL-1)   // 255
#define NBG 32         // batch groups
#define BGB 8          // batches per group
#define HCH 32         // h per chunk (=> 512 W2 cols per block)
#define TPB 1024
#define NJS 8          // phase-B j-split slices

typedef __attribute__((ext_vector_type(4))) float f32x4;   // packed fp32 (v_pk_fma_f32 pairs)

// fast tanh: 1 - 2/(e^{2x}+1). IDENTICAL to the r0 baseline (bit-exact frozen).
__device__ __forceinline__ float fast_tanh(float x) {
    float e = __expf(2.0f * x);
    return 1.0f - 2.0f / (e + 1.0f);
}

// coherence-point (device-coherent) access: bypasses the non-coherent
// per-XCD L2s. Used ONLY for the small cross-block z / hid exchange.
__device__ __forceinline__ float ld_coh(const float* p) {
    return __hip_atomic_load(p, __ATOMIC_RELAXED, __HIP_MEMORY_SCOPE_AGENT);
}
__device__ __forceinline__ float2 ld_coh2(const float* p) {
    union { unsigned long long u; float2 f; } cv;
    cv.u = __hip_atomic_load((const unsigned long long*)p,
                             __ATOMIC_RELAXED, __HIP_MEMORY_SCOPE_AGENT);
    return cv.f;
}
__device__ __forceinline__ void st_coh(float* p, float v) {
    __hip_atomic_store(p, v, __ATOMIC_RELAXED, __HIP_MEMORY_SCOPE_AGENT);
}

// 8-way sibling barrier, monotonic per-group counter (no reset).
__device__ __forceinline__ void bg_barrier(unsigned* cnt, unsigned target) {
    __syncthreads();
    if (threadIdx.x == 0) {
        __hip_atomic_fetch_add(cnt, 1u, __ATOMIC_RELAXED, __HIP_MEMORY_SCOPE_AGENT);
        while (__hip_atomic_load(cnt, __ATOMIC_RELAXED, __HIP_MEMORY_SCOPE_AGENT) < target)
            __builtin_amdgcn_s_sleep(1);
    }
    __syncthreads();
}

// ---------------------------------------------------------------------------
// persistent scan: 256 blocks = 32 bg x 8 hc, 1024 threads.
// LDS (147 KB) caps residency at 1 block/CU (16 waves) -> __launch_bounds__
// (TPB, 4) = 4 waves/EU raises the VGPR cap 64 -> 128 at ZERO occupancy cost.
// r5 spilled accumulators to scratch under the default 64-VGPR cap
// (FETCH_SIZE 100x, WRITE_SIZE 36x, VALUBusy 8.7%); this is the fix.
// NUMERICS BIT-IDENTICAL to the passing baseline (r5 reproduced its absmax
// exactly); only register budget + unroll depth changed this round.
// ---------------------------------------------------------------------------
__global__ void __launch_bounds__(TPB, 4)
k_scan(const float* __restrict__ us, const float* __restrict__ W1,
       const float* __restrict__ b1, const float* __restrict__ W2,
       const float* __restrict__ b2, float* __restrict__ zs,
       float* __restrict__ hidG, unsigned* __restrict__ barG) {
    __shared__ float smem[NJS * BGB * 512 + 2048 + 2048 + 512 + 128 + 32];
    float* psum    = smem;                         // [8][8][512]  128 KB
    float* pa      = smem;                         // alias [32][256] (phase A)
    float* z_loc   = smem + NJS * BGB * 512;       // [8][256]     8 KB
    float* hid_loc = z_loc + BGB * HH;             // [8][256]     8 KB
    float* b2s     = hid_loc + BGB * HH;           // [512]
    float* dvs     = b2s + 512;                    // [8][16]
    float* b1s     = dvs + 128;                    // [32]

    const int bg = blockIdx.x >> 3;
    const int hc = blockIdx.x & 7;                 // == XCD id under i%8 mapping:
    const int t  = threadIdx.x;                    // same-hc blocks share W2 slice in L2
    const int b0 = bg * BGB;
    const int h0 = hc * HCH;
    const int n0 = h0 * CC;                        // = hc*512

    // ---- one-time preload ----
    const int ajc = t >> 5;                        // 0..31
    const int ah  = t & 31;
    float w1r[8];
    #pragma unroll
    for (int r = 0; r < 8; r++)
        w1r[r] = W1[(size_t)(ajc * 8 + r) * HH + h0 + ah];
    for (int i = t; i < 512; i += TPB) b2s[i] = b2[n0 + i];
    if (t < HCH) b1s[t] = b1[h0 + t];
    __syncthreads();

    unsigned* cnt = barG + (size_t)bg * 64;        // 256-B line per group

    const int sb  = t >> 7;                        // staging: 0..7
    const int sj2 = (t & 127) << 1;                // 0,2,..,254
    const int jsp = t >> 7;                        // phase-B: 0..7
    const int ct  = (t & 127) << 2;                // 0..508
    const int col = t & 511;                       // dz indices
    const int bh  = (t >> 9) << 2;                 // 0 or 4

    for (int k = 0; k < NSTEP; k++) {
        const size_t zk = (size_t)k * (BB * HH);

        // ---- stage z_loc (coherent 8B, coalesced) + dvs ----
        {
            float2 v = ld_coh2(&zs[zk + (size_t)(b0 + sb) * HH + sj2]);
            *(float2*)&z_loc[sb * HH + sj2] = v;
        }
        if (t < BGB * CC) {
            int b = t >> 4, c = t & 15;
            int kk = (k < 1) ? 1 : k;
            float v = 1.0f;                        // c==0: ts diff == 1
            if (c > 0)
                v = us[((size_t)kk * BB + b0 + b) * (CC - 1) + c - 1]
                  - us[((size_t)(kk - 1) * BB + b0 + b) * (CC - 1) + c - 1];
            dvs[b * CC + c] = v;
        }
        __syncthreads();

        // ---- phase A: partial hid[b][h0+ah] over 8 j's (W1 in regs) ----
        // UNCHANGED (bit-exact).
        {
            float acc[BGB];
            #pragma unroll
            for (int b = 0; b < BGB; b++) acc[b] = 0.f;
            #pragma unroll
            for (int r2 = 0; r2 < 2; r2++) {
                #pragma unroll
                for (int b = 0; b < BGB; b++) {
                    float4 zv = *(const float4*)&z_loc[b * HH + ajc * 8 + r2 * 4];
                    acc[b] += zv.x * w1r[r2 * 4 + 0] + zv.y * w1r[r2 * 4 + 1]
                            + zv.z * w1r[r2 * 4 + 2] + zv.w * w1r[r2 * 4 + 3];
                }
            }
            #pragma unroll
            for (int b = 0; b < BGB; b++)
                pa[ajc * 256 + b * HCH + ah] = acc[b];  // lane-stride 1: free
        }
        __syncthreads();
        if (t < BGB * HCH) {                       // reduce 32 partials, relu, publish
            float s = b1s[t & 31];
            #pragma unroll
            for (int q = 0; q < 32; q++) s += pa[q * 256 + t];  // stride 1
            st_coh(&hidG[(size_t)(b0 + (t >> 5)) * HH + h0 + (t & 31)],
                   fmaxf(s, 0.f));
        }
        bg_barrier(cnt, 8u * (2u * (unsigned)k + 1u));   // hid complete

        // ---- stage hid_loc NATURAL layout (coherent 8B, coalesced) ----
        {
            float2 v = ld_coh2(&hidG[(size_t)(b0 + sb) * HH + sj2]);
            *(float2*)&hid_loc[sb * HH + sj2] = v;
        }
        __syncthreads();

        // ---- phase B: hid(8x256) @ W2-slice(256x512) ----
        // j-step-4, h-values as float4 broadcasts from natural hid_loc rows.
        // Each acc[b][c] chain receives the SAME products in the SAME j-order
        // as the baseline -> bit-identical (PROVEN by r5's exact absmax).
        // unroll 2 bounds the hoisted-load live range under the 128-VGPR cap.
        {
            f32x4 acc[BGB];
            #pragma unroll
            for (int b = 0; b < BGB; b++) acc[b] = (f32x4){0.f, 0.f, 0.f, 0.f};
            const int jb = jsp * 32;
            const float* w2p = &W2[(size_t)jb * HC + n0 + ct];
            #pragma unroll 2
            for (int jq = 0; jq < 32; jq += 4) {
                f32x4 w0 = *(const f32x4*)&w2p[(size_t)(jq + 0) * HC];
                f32x4 w1 = *(const f32x4*)&w2p[(size_t)(jq + 1) * HC];
                f32x4 w2v = *(const f32x4*)&w2p[(size_t)(jq + 2) * HC];
                f32x4 w3 = *(const f32x4*)&w2p[(size_t)(jq + 3) * HC];
                #pragma unroll
                for (int b = 0; b < BGB; b++) {
                    f32x4 h4 = *(const f32x4*)&hid_loc[b * HH + jb + jq]; // bcast
                    acc[b] = h4.x * w0  + acc[b];
                    acc[b] = h4.y * w1  + acc[b];
                    acc[b] = h4.z * w2v + acc[b];
                    acc[b] = h4.w * w3  + acc[b];
                }
            }
            #pragma unroll
            for (int b = 0; b < BGB; b++)
                *(f32x4*)&psum[((jsp * BGB + b) << 9) + ct] = acc[b];
        }
        __syncthreads();

        // ---- dz + z update: lane owns col; 16-lane shfl c-reduction ----
        // UNCHANGED (bit-exact).
        {
            #pragma unroll
            for (int q = 0; q < 4; q++) {
                int b = bh + q;
                float g = b2s[col];
                #pragma unroll
                for (int s = 0; s < NJS; s++)
                    g += psum[((s * BGB + b) << 9) + col];   // stride-1
                float v = fast_tanh(g) * dvs[b * CC + (col & 15)];
                v += __shfl_xor(v, 1);
                v += __shfl_xor(v, 2);
                v += __shfl_xor(v, 4);
                v += __shfl_xor(v, 8);
                if ((col & 15) == 0) {
                    int hl = col >> 4;
                    st_coh(&zs[zk + (size_t)(BB * HH) + (size_t)(b0 + b) * HH + h0 + hl],
                           z_loc[b * HH + h0 + hl] + v);     // dt == 1
                }
            }
        }
        bg_barrier(cnt, 8u * (2u * (unsigned)k + 2u));       // z[k+1] complete
    }
}

// ---------------------------------------------------------------------------
// out = tanh(z_seq @ dW1 + db1) @ dW2 + db2   — UNCHANGED from baseline.
// ---------------------------------------------------------------------------
__global__ void k_out(const float* __restrict__ zseq, const float* __restrict__ dW1,
                      const float* __restrict__ db1, const float* __restrict__ dW2,
                      const float* __restrict__ db2, float* __restrict__ out) {
    __shared__ float zt[16][HH];       // 16 KB
    __shared__ float act[16][2 * HH];  // 32 KB
    int r0 = blockIdx.x * 16;
    int t  = threadIdx.x;
    {
        const float4* src = (const float4*)(zseq + (size_t)r0 * HH);
        float4* dst = (float4*)&zt[0][0];
        for (int i = t; i < 1024; i += 256) dst[i] = src[i];
    }
    __syncthreads();
    {   // phase 1: act = tanh(z @ dW1 + db1), 512 cols
        int c0  = (t & 127) * 4;
        int rr0 = (t >> 7) * 8;
        float a[8][4];
        #pragma unroll
        for (int i = 0; i < 8; i++)
            #pragma unroll
            for (int q = 0; q < 4; q++) a[i][q] = 0.f;
        for (int j = 0; j < HH; j++) {
            float4 w = *(const float4*)&dW1[(size_t)j * 2 * HH + c0];
            #pragma unroll
            for (int i = 0; i < 8; i++) {
                float zv = zt[rr0 + i][j];
                a[i][0] += zv * w.x; a[i][1] += zv * w.y;
                a[i][2] += zv * w.z; a[i][3] += zv * w.w;
            }
        }
        float4 bias = *(const float4*)&db1[c0];
        #pragma unroll
        for (int i = 0; i < 8; i++) {
            act[rr0 + i][c0 + 0] = fast_tanh(a[i][0] + bias.x);
            act[rr0 + i][c0 + 1] = fast_tanh(a[i][1] + bias.y);
            act[rr0 + i][c0 + 2] = fast_tanh(a[i][2] + bias.z);
            act[rr0 + i][c0 + 3] = fast_tanh(a[i][3] + bias.w);
        }
    }
    __syncthreads();
    {   // phase 2: out = act @ dW2 + db2
        int rl = t >> 4;
        int y2 = t & 15;
        float o0 = 0.f, o1 = 0.f;
        #pragma unroll 4
        for (int j = 0; j < 2 * HH; j++) {
            float av = act[rl][j];
            float2 w = *(const float2*)&dW2[(size_t)j * YY + y2 * 2];
            o0 += av * w.x; o1 += av * w.y;
        }
        float2 bias = *(const float2*)&db2[y2 * 2];
        out[(size_t)(r0 + rl) * YY + y2 * 2]     = o0 + bias.x;
        out[(size_t)(r0 + rl) * YY + y2 * 2 + 1] = o1 + bias.y;
    }
}

// ---------------------------------------------------------------------------
extern "C" void kernel_launch(void* const* d_in, const int* in_sizes, int n_in,
                              void* d_out, int out_size, void* d_ws, size_t ws_size,
                              hipStream_t stream) {
    const float* us  = (const float*)d_in[1];
    const float* h0  = (const float*)d_in[2];
    const float* W1  = (const float*)d_in[3];
    const float* b1  = (const float*)d_in[4];
    const float* W2  = (const float*)d_in[5];
    const float* b2  = (const float*)d_in[6];
    const float* dW1 = (const float*)d_in[7];
    const float* db1 = (const float*)d_in[8];
    const float* dW2 = (const float*)d_in[9];
    const float* db2 = (const float*)d_in[10];
    float* out = (float*)d_out;

    float* zs   = (float*)d_ws;                          // L*B*H = 64 MB, [l*B+b][h]
    float* hidG = zs + (size_t)LL * BB * HH;             // B*H   = 256 KB
    unsigned* barG = (unsigned*)(hidG + (size_t)BB * HH); // 32 x 256 B = 8 KB

    hipMemcpyAsync(zs, h0, (size_t)BB * HH * sizeof(float),
                   hipMemcpyDeviceToDevice, stream);
    hipMemsetAsync(barG, 0, NBG * 64 * sizeof(unsigned), stream);

    k_scan<<<NBG * 8, TPB, 0, stream>>>(us, W1, b1, W2, b2, zs, hidG, barG);
    k_out<<<LL * BB / 16, 256, 0, stream>>>(zs, dW1, db1, dW2, db2, out);
}